// Round 11
// baseline (1010.278 us; speedup 1.0000x reference)
//
#include <hip/hip_runtime.h>
#include <math.h>

#define B_   32
#define L_   1024
#define C_   32
#define D_   512
#define SEG_ 16
#define SX_  64
#define N_   1024   // B*C

typedef _Float16 f16x8 __attribute__((ext_vector_type(8)));
typedef _Float16 f16x4 __attribute__((ext_vector_type(4)));
typedef float    f32x4 __attribute__((ext_vector_type(4)));

__device__ __forceinline__ void stage16(const void* g, void* l) {
    __builtin_amdgcn_global_load_lds((const __attribute__((address_space(1))) void*)g,
                                     (__attribute__((address_space(3))) void*)l, 16, 0, 0);
}
// sc0|sc1: device-coherent (coherence-point) load -> LDS, cross-XCD safe
__device__ __forceinline__ void stage16c(const void* g, void* l) {
    __builtin_amdgcn_global_load_lds((const __attribute__((address_space(1))) void*)g,
                                     (__attribute__((address_space(3))) void*)l, 16, 0, 17);
}
__device__ __forceinline__ void store_h16(void* p, float v) {
    _Float16 h = (_Float16)v;
    unsigned short us;
    __builtin_memcpy(&us, &h, 2);
    unsigned int uu = us;
    asm volatile("global_store_short %0, %1, off sc0 sc1" :: "v"(p), "v"(uu) : "memory");
}

// ---------------------------------------------------------------------------
// prep: x (B,L,C) -> xs_seg, xt_seg fp32 (step, n, seg); channel-axis moving
// mean (reference semantics), window 25, edge replication.
// ---------------------------------------------------------------------------
__global__ __launch_bounds__(256) void prep_kernel(const float* __restrict__ x,
                                                   float* __restrict__ xs_seg,
                                                   float* __restrict__ xt_seg) {
    int b = blockIdx.x >> 2;
    int t = ((blockIdx.x & 3) << 8) + threadIdx.x;
    const float* xb    = x + (size_t)b * (L_ * C_);
    const float* xrow  = xb + (size_t)t * C_;
    const float* xlast = xb + (size_t)(L_ - 1) * C_;

    float diff[C_];
#pragma unroll
    for (int c = 0; c < C_; ++c) diff[c] = xrow[c] - xlast[c];
    float ps[C_ + 1];
    ps[0] = 0.f;
#pragma unroll
    for (int c = 0; c < C_; ++c) ps[c + 1] = ps[c] + diff[c];

    int s = t >> 4, q = t & 15;
#pragma unroll
    for (int c = 0; c < C_; ++c) {
        int lo = c - 12, hi = c + 12;
        float sum = ps[(hi < 31 ? hi : 31) + 1] - ps[lo > 0 ? lo : 0];
        if (lo < 0)  sum += (float)(-lo)     * diff[0];
        if (hi > 31) sum += (float)(hi - 31) * diff[31];
        float mean = sum * (1.0f / 25.0f);
        size_t idx = ((size_t)s * N_ + (size_t)(b * C_ + c)) * SEG_ + q;
        xt_seg[idx] = mean;
        xs_seg[idx] = diff[c] - mean;
    }
}

// ---------------------------------------------------------------------------
// emb: ALL 64 steps. emb_buf[sl 64][gru 2][n 1024][512] f16
//    = relu(xseg @ W_emb^T + b_emb).  grid 2048.
// ---------------------------------------------------------------------------
__global__ __launch_bounds__(256) void emb_kernel(
    const float* __restrict__ xs_seg, const float* __restrict__ xt_seg,
    const float* __restrict__ W_emb, const float* __restrict__ b_emb,
    _Float16* __restrict__ emb_buf) {
    int bid = blockIdx.x;
    int gru = bid >> 10, sl = (bid >> 4) & 63, nch = bid & 15;
    int n0 = nch * 64;
    const float* xseg = gru ? xt_seg : xs_seg;
    __shared__ float xl[64 * 16];
    int tid = threadIdx.x;
    const float* src = xseg + ((size_t)sl * N_ + n0) * SEG_;
    for (int i = tid; i < 1024; i += 256) xl[i] = src[i];

    int kg = tid & 127;
    int rh = tid >> 7;
    float w[4][16], bb[4];
#pragma unroll
    for (int i = 0; i < 4; ++i) {
        int k = kg * 4 + i;
        const float4* wr = (const float4*)(W_emb + (size_t)k * 16);
#pragma unroll
        for (int v = 0; v < 4; ++v) {
            float4 tt = wr[v];
            w[i][v * 4 + 0] = tt.x; w[i][v * 4 + 1] = tt.y;
            w[i][v * 4 + 2] = tt.z; w[i][v * 4 + 3] = tt.w;
        }
        bb[i] = b_emb[k];
    }
    __syncthreads();
    _Float16* dst = emb_buf + ((size_t)(sl * 2 + gru) * N_ + n0) * D_ + kg * 4;
    for (int r = 0; r < 32; ++r) {
        int row = rh * 32 + r;
        float a0 = bb[0], a1 = bb[1], a2 = bb[2], a3 = bb[3];
#pragma unroll
        for (int q = 0; q < 16; ++q) {
            float xv = xl[row * 16 + q];
            a0 = fmaf(xv, w[0][q], a0);
            a1 = fmaf(xv, w[1][q], a1);
            a2 = fmaf(xv, w[2][q], a2);
            a3 = fmaf(xv, w[3][q], a3);
        }
        f16x4 v;
        v[0] = (_Float16)(a0 > 0.f ? a0 : 0.f);
        v[1] = (_Float16)(a1 > 0.f ? a1 : 0.f);
        v[2] = (_Float16)(a2 > 0.f ? a2 : 0.f);
        v[3] = (_Float16)(a3 > 0.f ? a3 : 0.f);
        *(f16x4*)(dst + (size_t)row * D_) = v;
    }
}

// ---------------------------------------------------------------------------
// Generic weight pack, pre-swizzled for chain: [gru][m 8][kt 4][chunk 3072][8]
// chunk c: gc=c>>4, s=c&15, q=s^(gc&15); k = kt*128 + q*8 + fi;
// gc = wn*48+gate*16+jl, j = member*64+wn*16+jl. Used for BOTH Wih and Whh.
// ---------------------------------------------------------------------------
__global__ __launch_bounds__(256) void pack_w5_kernel(
    const float* __restrict__ W_s, const float* __restrict__ W_t,
    _Float16* __restrict__ wp) {
    int e = blockIdx.x * 256 + threadIdx.x;     // 2*8*4*3072*8 = 1572864
    int fi = e & 7;
    int t = e >> 3;
    int c = t % 3072;
    int t2 = t / 3072;
    int kt = t2 & 3;
    int t3 = t2 >> 2;
    int member = t3 & 7, gru = t3 >> 3;
    int gc = c >> 4, s = c & 15;
    int q = s ^ (gc & 15);
    int k = kt * 128 + q * 8 + fi;
    int wn = gc / 48, r2 = gc % 48;
    int gate = r2 >> 4, jl = r2 & 15;
    int j = member * 64 + wn * 16 + jl;
    const float* W = gru ? W_t : W_s;
    wp[e] = (_Float16)W[(size_t)(gate * 512 + j) * 512 + k];
}

// pe[gru][n][512] f16
__global__ __launch_bounds__(256) void pack_pe_kernel(
    const float* __restrict__ pos_s, const float* __restrict__ ch_s,
    const float* __restrict__ pos_t, const float* __restrict__ ch_t,
    _Float16* __restrict__ pe) {
    int e = blockIdx.x * 256 + threadIdx.x;     // 2*1024*512
    int k = e & 511;
    int n = (e >> 9) & 1023;
    int gru = e >> 19;
    int c = n & 31;
    const float* pos = gru ? pos_t : pos_s;
    const float* ch  = gru ? ch_t  : ch_s;
    float v = (k < 256) ? pos[k] : ch[c * 256 + (k - 256)];
    pe[e] = (_Float16)v;
}

// ---------------------------------------------------------------------------
// Fused persistent chain: 256 blocks (1/CU) x 512 thr, ONE launch for all
// 64 scan steps + decoder step (it==64 -> A source = pe).
// Per step: A-phase gi = emb(it)xWih (NO h dependency -> runs in the barrier
// wait bubble, at the tail of the previous iteration), then spin for h(it),
// then B-phase gh = h(it)xWhh. n-gate: gi_n stays in acc[..][2], gh_n goes
// to separate acc_hn (r multiplies only the hidden part). h exchange sc0/sc1;
// per-chain monotone barrier, fetch_add UNCONDITIONAL (R8 lesson).
// XCD locality: member = bid&7 = XCD id -> each XCD's 4 weight slices
// (Wih+Whh x 2 gru, 768 KB) stay L2-resident for the whole launch.
// ---------------------------------------------------------------------------
__global__ __launch_bounds__(512) void gru_chain_kernel(
    const _Float16* __restrict__ wih_pk,   // [gru][m8][kt4][3072][8]
    const _Float16* __restrict__ whh_pk,   // same layout
    const _Float16* __restrict__ emb,      // [64][gru][1024][512]
    const _Float16* __restrict__ pe,       // [gru][1024][512]
    const float* __restrict__ bih_s, const float* __restrict__ bhh_s,
    const float* __restrict__ bih_t, const float* __restrict__ bhh_t,
    _Float16* __restrict__ hbf0, _Float16* __restrict__ hbf1,
    unsigned* __restrict__ flags, int nsteps) {
    __shared__ __align__(16) char sA[2][16384];
    __shared__ __align__(16) char sB[2][49152];
    int bid = blockIdx.x;
    int member = bid & 7, chain = bid >> 3;
    int Mt = chain & 15, gru = chain >> 4;
    int tid = threadIdx.x, w = tid >> 6, lane = tid & 63;
    int ml = lane & 15, qq = lane >> 4;
    int wm = w & 1, wn = w >> 1;

    const char* BbI = (const char*)wih_pk + (size_t)(gru * 8 + member) * 196608;
    const char* BbH = (const char*)whh_pk + (size_t)(gru * 8 + member) * 196608;
    const char* h0 = (const char*)hbf0 + ((size_t)gru * N_ + Mt * 64) * 1024;
    const char* h1 = (const char*)hbf1 + ((size_t)gru * N_ + Mt * 64) * 1024;
    const char* embB = (const char*)emb + ((size_t)gru * N_ + Mt * 64) * 1024;
    const char* peB  = (const char*)pe  + ((size_t)gru * N_ + Mt * 64) * 1024;

    // A staging map (64 rows x 16 chunks of 16B per 128-K tile, XOR-16)
    int aRow[2], aQ[2];
#pragma unroll
    for (int r = 0; r < 2; ++r) {
        int c = r * 512 + tid;
        aRow[r] = c >> 4;
        aQ[r] = (c & 15) ^ (aRow[r] & 15);
    }

    // fragment offsets
    int offA[2][4], offB[3][4];
#pragma unroll
    for (int rt = 0; rt < 2; ++rt) {
        int row = wm * 32 + rt * 16 + ml;
#pragma unroll
        for (int kf = 0; kf < 4; ++kf)
            offA[rt][kf] = row * 256 + ((kf * 4 + qq) ^ (row & 15)) * 16;
    }
#pragma unroll
    for (int g = 0; g < 3; ++g) {
        int gc = wn * 48 + g * 16 + ml;
#pragma unroll
        for (int kf = 0; kf < 4; ++kf)
            offB[g][kf] = gc * 256 + ((kf * 4 + qq) ^ (gc & 15)) * 16;
    }

    const float* bi = gru ? bih_t : bih_s;
    const float* bh = gru ? bhh_t : bhh_s;
    int j = member * 64 + wn * 16 + ml;
    float bir = bi[j], biz = bi[D_ + j], bin = bi[2 * D_ + j];
    float bhr = bh[j], bhz = bh[D_ + j], bhn = bh[2 * D_ + j];
    float hp[2][4];
#pragma unroll
    for (int rt = 0; rt < 2; ++rt)
#pragma unroll
        for (int reg = 0; reg < 4; ++reg) {
            int row = Mt * 64 + wm * 32 + rt * 16 + qq * 4 + reg;
            hp[rt][reg] = (float)hbf0[((size_t)gru * N_ + row) * D_ + j];
        }

    unsigned* flag = flags + chain * 32;

    f32x4 acc[2][3], acc_hn[2];

    auto stageB = [&](const char* Bb, int kt, char* dst) {
#pragma unroll
        for (int r = 0; r < 6; ++r)
            stage16(Bb + (size_t)kt * 49152 + (size_t)(r * 512 + tid) * 16,
                    dst + r * 8192 + w * 1024);
    };
    auto stageA = [&](const char* ab, int kt, char* dst) {   // emb/pe (plain)
#pragma unroll
        for (int r = 0; r < 2; ++r)
            stage16(ab + (size_t)aRow[r] * 1024 + kt * 256 + aQ[r] * 16,
                    dst + r * 8192 + w * 1024);
    };
    auto stageAc = [&](const char* ab, int kt, char* dst) {  // h (coherent)
#pragma unroll
        for (int r = 0; r < 2; ++r)
            stage16c(ab + (size_t)aRow[r] * 1024 + kt * 256 + aQ[r] * 16,
                    dst + r * 8192 + w * 1024);
    };

    // A-phase: acc = emb(step) x Wih (all 3 gates). 4 tiles, dbuf.
    auto runA = [&](const char* ab) {
        stageB(BbI, 0, sB[0]); stageA(ab, 0, sA[0]);
        stageB(BbI, 1, sB[1]); stageA(ab, 1, sA[1]);
#pragma unroll
        for (int rt = 0; rt < 2; ++rt)
#pragma unroll
            for (int g = 0; g < 3; ++g) {
                f32x4 z = {0.f, 0.f, 0.f, 0.f};
                acc[rt][g] = z;
            }
        for (int i = 0; i < 4; ++i) {
            __syncthreads();
            if (i == 1 || i == 2) {
                stageB(BbI, i + 1, sB[(i + 1) & 1]);
                stageA(ab, i + 1, sA[(i + 1) & 1]);
                asm volatile("s_waitcnt vmcnt(8)" ::: "memory");
            } else if (i == 0) {
                asm volatile("s_waitcnt vmcnt(8)" ::: "memory");
            } else {
                asm volatile("s_waitcnt vmcnt(0)" ::: "memory");
            }
            __syncthreads();
            const char* cA = sA[i & 1];
            const char* cB = sB[i & 1];
            f16x8 a0[4], a1[4];
#pragma unroll
            for (int kf = 0; kf < 4; ++kf) {
                a0[kf] = *(const f16x8*)(cA + offA[0][kf]);
                a1[kf] = *(const f16x8*)(cA + offA[1][kf]);
            }
#pragma unroll
            for (int g = 0; g < 3; ++g)
#pragma unroll
                for (int kf = 0; kf < 4; ++kf) {
                    f16x8 b = *(const f16x8*)(cB + offB[g][kf]);
                    acc[0][g] = __builtin_amdgcn_mfma_f32_16x16x32_f16(a0[kf], b, acc[0][g], 0, 0, 0);
                    acc[1][g] = __builtin_amdgcn_mfma_f32_16x16x32_f16(a1[kf], b, acc[1][g], 0, 0, 0);
                }
        }
    };

    runA(embB);   // gi for step 0

    for (int it = 0; it < nsteps; ++it) {
        const char* hin = (it & 1) ? h1 : h0;
        _Float16* hout  = (it & 1) ? hbf0 : hbf1;

        // Whh kt0 has no h dependency -> stage before the spin
        stageB(BbH, 0, sB[0]);
        if (tid == 0 && it > 0) {
            unsigned tgt = 8u * (unsigned)it;
            int guard = 0;
            while (__hip_atomic_load(flag, __ATOMIC_RELAXED, __HIP_MEMORY_SCOPE_AGENT) < tgt) {
                __builtin_amdgcn_s_sleep(1);
                if (++guard > (1 << 22)) break;   // bail: fail, don't hang
            }
        }
        __syncthreads();
        // h(it) now visible: stage h kt0, then kt1 (B then A per kt)
        stageAc(hin, 0, sA[0]);
        stageB(BbH, 1, sB[1]);
        stageAc(hin, 1, sA[1]);
#pragma unroll
        for (int rt = 0; rt < 2; ++rt) {
            f32x4 z = {0.f, 0.f, 0.f, 0.f};
            acc_hn[rt] = z;
        }
        for (int i = 0; i < 4; ++i) {
            __syncthreads();
            if (i == 1 || i == 2) {
                stageB(BbH, i + 1, sB[(i + 1) & 1]);
                stageAc(hin, i + 1, sA[(i + 1) & 1]);
                asm volatile("s_waitcnt vmcnt(8)" ::: "memory");
            } else if (i == 0) {
                asm volatile("s_waitcnt vmcnt(8)" ::: "memory");
            } else {
                asm volatile("s_waitcnt vmcnt(0)" ::: "memory");
            }
            __syncthreads();
            const char* cA = sA[i & 1];
            const char* cB = sB[i & 1];
            f16x8 a0[4], a1[4];
#pragma unroll
            for (int kf = 0; kf < 4; ++kf) {
                a0[kf] = *(const f16x8*)(cA + offA[0][kf]);
                a1[kf] = *(const f16x8*)(cA + offA[1][kf]);
            }
#pragma unroll
            for (int kf = 0; kf < 4; ++kf) {
                f16x8 b0 = *(const f16x8*)(cB + offB[0][kf]);
                acc[0][0] = __builtin_amdgcn_mfma_f32_16x16x32_f16(a0[kf], b0, acc[0][0], 0, 0, 0);
                acc[1][0] = __builtin_amdgcn_mfma_f32_16x16x32_f16(a1[kf], b0, acc[1][0], 0, 0, 0);
                f16x8 b1 = *(const f16x8*)(cB + offB[1][kf]);
                acc[0][1] = __builtin_amdgcn_mfma_f32_16x16x32_f16(a0[kf], b1, acc[0][1], 0, 0, 0);
                acc[1][1] = __builtin_amdgcn_mfma_f32_16x16x32_f16(a1[kf], b1, acc[1][1], 0, 0, 0);
                f16x8 b2 = *(const f16x8*)(cB + offB[2][kf]);
                acc_hn[0] = __builtin_amdgcn_mfma_f32_16x16x32_f16(a0[kf], b2, acc_hn[0], 0, 0, 0);
                acc_hn[1] = __builtin_amdgcn_mfma_f32_16x16x32_f16(a1[kf], b2, acc_hn[1], 0, 0, 0);
            }
        }

        // fused GRU epilogue: acc[..][0,1] = gi+gh (r,z); acc[..][2] = gi_n;
        // acc_hn = gh_n
#pragma unroll
        for (int rt = 0; rt < 2; ++rt)
#pragma unroll
            for (int reg = 0; reg < 4; ++reg) {
                int row = Mt * 64 + wm * 32 + rt * 16 + qq * 4 + reg;
                float r = 1.f / (1.f + __expf(-(acc[rt][0][reg] + bir + bhr)));
                float z = 1.f / (1.f + __expf(-(acc[rt][1][reg] + biz + bhz)));
                float nn = tanhf(acc[rt][2][reg] + bin + r * (acc_hn[rt][reg] + bhn));
                float hv = (1.f - z) * nn + z * hp[rt][reg];
                hp[rt][reg] = hv;
                store_h16(hout + ((size_t)gru * N_ + row) * D_ + j, hv);
            }

        asm volatile("s_waitcnt vmcnt(0)" ::: "memory");   // drain h stores
        __syncthreads();
        if (tid == 0)
            __hip_atomic_fetch_add(flag, 1u, __ATOMIC_RELAXED, __HIP_MEMORY_SCOPE_AGENT);
        if (it < nsteps - 1) {
            // bubble-fill: gi for the NEXT step (no h dependency)
            const char* ab = (it + 1 < 64) ? (embB + (size_t)(it + 1) * 2097152) : peB;
            runA(ab);
        }
    }
}

// ---------------------------------------------------------------------------
__global__ __launch_bounds__(256) void head_kernel(
    const _Float16* __restrict__ hs2, const _Float16* __restrict__ ht2,
    const float* __restrict__ Wps, const float* __restrict__ bps,
    const float* __restrict__ Wpt, const float* __restrict__ bpt,
    const float* __restrict__ x, float* __restrict__ out) {
    int g = blockIdx.x * 256 + threadIdx.x;
    int n = g >> 4, p = g & 15;
    int b = n >> 5, c = n & 31;
    const _Float16* hs = hs2 + (size_t)n * D_;
    const _Float16* ht = ht2 + (size_t)n * D_;
    const float* ws = Wps + (size_t)p * D_;
    const float* wt = Wpt + (size_t)p * D_;
    float acc = bps[p] + bpt[p];
    for (int k = 0; k < D_; ++k)
        acc += (float)hs[k] * ws[k] + (float)ht[k] * wt[k];
    float last = x[((size_t)b * L_ + (L_ - 1)) * C_ + c];
    out[((size_t)b * SEG_ + p) * C_ + c] = acc + last;
}

// ---------------------------------------------------------------------------
extern "C" void kernel_launch(void* const* d_in, const int* in_sizes, int n_in,
                              void* d_out, int out_size, void* d_ws, size_t ws_size,
                              hipStream_t stream) {
    const float* x     = (const float*)d_in[0];
    const float* W_emb = (const float*)d_in[1];
    const float* b_emb = (const float*)d_in[2];
    const float* Wih_s = (const float*)d_in[3];
    const float* Whh_s = (const float*)d_in[4];
    const float* bih_s = (const float*)d_in[5];
    const float* bhh_s = (const float*)d_in[6];
    const float* Wih_t = (const float*)d_in[7];
    const float* Whh_t = (const float*)d_in[8];
    const float* bih_t = (const float*)d_in[9];
    const float* bhh_t = (const float*)d_in[10];
    const float* pos_s = (const float*)d_in[11];
    const float* ch_s  = (const float*)d_in[12];
    const float* pos_t = (const float*)d_in[13];
    const float* ch_t  = (const float*)d_in[14];
    const float* Wps   = (const float*)d_in[15];
    const float* bps   = (const float*)d_in[16];
    const float* Wpt   = (const float*)d_in[17];
    const float* bpt   = (const float*)d_in[18];
    float* out = (float*)d_out;

    char* p = (char*)d_ws;
    float* xs_seg = (float*)p;          p += (size_t)SX_ * N_ * SEG_ * 4;        // 4 MB
    float* xt_seg = (float*)p;          p += (size_t)SX_ * N_ * SEG_ * 4;        // 4 MB
    _Float16* emb_buf = (_Float16*)p;   p += (size_t)64 * 2 * N_ * D_ * 2;       // 128 MB
    _Float16* pe_buf  = (_Float16*)p;   p += (size_t)2 * N_ * D_ * 2;            // 2 MB
    _Float16* wih_pk5 = (_Float16*)p;   p += (size_t)2 * 8 * 4 * 3072 * 8 * 2;   // 3 MB
    _Float16* whh_pk5 = (_Float16*)p;   p += (size_t)2 * 8 * 4 * 3072 * 8 * 2;   // 3 MB
    _Float16* hbf0 = (_Float16*)p;      p += (size_t)2 * N_ * D_ * 2;            // 2 MB
    _Float16* hbf1 = (_Float16*)p;      p += (size_t)2 * N_ * D_ * 2;            // 2 MB
    unsigned* flags = (unsigned*)p;     p += 32 * 32 * 4;                        // 4 KB

    hipMemsetAsync(hbf0, 0, (size_t)2 * N_ * D_ * 2, stream);
    hipMemsetAsync(flags, 0, 32 * 32 * 4, stream);

    pack_w5_kernel<<<6144, 256, 0, stream>>>(Wih_s, Wih_t, wih_pk5);
    pack_w5_kernel<<<6144, 256, 0, stream>>>(Whh_s, Whh_t, whh_pk5);
    pack_pe_kernel<<<4096, 256, 0, stream>>>(pos_s, ch_s, pos_t, ch_t, pe_buf);
    prep_kernel<<<B_ * 4, 256, 0, stream>>>(x, xs_seg, xt_seg);
    emb_kernel<<<2048, 256, 0, stream>>>(xs_seg, xt_seg, W_emb, b_emb, emb_buf);

    // one persistent launch: 64 scan steps + decoder (it=64 -> pe)
    gru_chain_kernel<<<256, 512, 0, stream>>>(
        wih_pk5, whh_pk5, emb_buf, pe_buf,
        bih_s, bhh_s, bih_t, bhh_t, hbf0, hbf1, flags, 65);

    head_kernel<<<N_ * SEG_ / 256, 256, 0, stream>>>(
        hbf1, hbf1 + (size_t)N_ * D_, Wps, bps, Wpt, bpt, x, out);
}